// Round 10
// baseline (209.261 us; speedup 1.0000x reference)
//
#include <hip/hip_runtime.h>
#include <hip/hip_bf16.h>
#include <stdint.h>

#define M_TIME 64
#define N_DICT 20000
#define B_VOX  8192

#define NTILES 313    // ceil(20000/64); last tile padded with zeros

typedef _Float16 v8h __attribute__((ext_vector_type(8)));   // 8 f16 (4 VGPRs)
typedef float    v4f __attribute__((ext_vector_type(4)));
typedef float    v2f __attribute__((ext_vector_type(2)));
typedef float    v16f __attribute__((ext_vector_type(16)));

__device__ __forceinline__ unsigned long long u64max(unsigned long long a, unsigned long long b) { return a > b ? a : b; }
__device__ __forceinline__ unsigned umin32(unsigned a, unsigned b) { return a < b ? a : b; }
__device__ __forceinline__ unsigned umax32(unsigned a, unsigned b) { return a > b ? a : b; }
// median of 3 == second-largest of 3: one VOP3 op (pure reg computation).
__device__ __forceinline__ unsigned umed3(unsigned a, unsigned b, unsigned c) {
    unsigned d;
    asm("v_med3_u32 %0, %1, %2, %3" : "=v"(d) : "v"(a), "v"(b), "v"(c));
    return d;
}

// ---------------------------------------------------------------------------
// Prepass: convert y to f16 ONCE, packed in fragment order.
// yp[T] layout == [arr(2)][q = k>>3 (8)][n(64)][j(8 f16)]  (16 KB/tile):
// fr = (arr*2+h)*4+quad == arr*8 + (k>>3), so the SAME buffer serves both
// the 16x16x32 frags (h,quad) and the 32x32x16 frags (q = ks*2 + hk).
// ---------------------------------------------------------------------------
__global__ __launch_bounds__(256) void split_y(
    const float* __restrict__ yr, const float* __restrict__ yi,
    v8h* __restrict__ yp)
{
    const int u = blockIdx.x * 256 + threadIdx.x;   // [arr][T][j(8)][n_l(64)]
    const int n_l = u & 63;
    const int j   = (u >> 6) & 7;       // fragment sub-row: k = j*8 .. j*8+7
    const int T   = (u >> 9) % NTILES;
    const int arr = u / (NTILES * 512);
    if (arr > 1) return;
    const float* P = arr ? yi : yr;
    const int n_g = T * 64 + n_l;
    v8h V;
#pragma unroll
    for (int c = 0; c < 8; ++c) {
        float v = 0.f;
        if (n_g < N_DICT) v = P[(j * 8 + c) * N_DICT + n_g];
        V[c] = (_Float16)v;
    }
    const int fr = (arr * 2 + (j >> 2)) * 4 + (j & 3);   // == arr*8 + j
    yp[((size_t)T * 16 + fr) * 64 + n_l] = V;
}

// ---------------------------------------------------------------------------
// Phase A: f16 1-term MFMA GEMM + per-chunk top-2 (u32 packed comparator).
// Hypothesis ledger (all at the same 42-43% MfmaUtil wall, 87-95 us):
// barrier drain (R21), emission order (R22), occupancy 28-37% (R20/22),
// load latency (R23 dbuf), L1 frag traffic (R24) - ALL REFUTED. Fitted
// issue rate: 1 MFMA per 10.5 cyc/CU vs 4.85 pipe rate; m06's 2-PF ubench
// ran 8 waves/SIMD vs our 2.25 -> per-wave MFMA CADENCE is the survivor.
// R25: 32x32x16 shape. Wave owns 32n x 32vox x 4 combos -> 16 MFMAs/tile
// (was 32), each 2x FLOP at the faster 32x32 rate (2382-2495 vs 2075 TF).
// Pipe floor 40.5 -> 33.7 us; issue events halved. Epilogue cost/lane
// unchanged (16 sims); candidate protocol unchanged; rescore untouched.
// C/D: col=lane&31, row=(reg&3)+8*(reg>>2)+4*(lane>>5)  [HW: m74/m101].
// A: row=lane&31, k=(lane>>5)*8+j.  B: col=lane&31, k=(lane>>5)*8+j.
// ---------------------------------------------------------------------------
__global__ __launch_bounds__(256, 2) void gemm_pre(
    const float* __restrict__ ir, const float* __restrict__ ii,
    const v8h* __restrict__ yp,
    unsigned* __restrict__ cand, int tpc, int slots)
{
    __shared__ unsigned xm[2][32][2];       // [vh][vox col][a1,a2]  512 B

    const int tid  = threadIdx.x;
    const int wave = tid >> 6, lane = tid & 63;
    const int col  = lane & 31, hk = lane >> 5;  // hk: k-octet / row-offset sel
    const int vh   = wave >> 1, nh = wave & 1;   // vox half / n half
    const int vox_w = blockIdx.x * 64;
    const int chunk = blockIdx.y;
    const int T0 = chunk * tpc;
    const int T1 = (T0 + tpc < NTILES) ? T0 + tpc : NTILES;

    // ---- persistent input B-frags: [arr][ks], vox = vox_w+vh*32+col ----
    v8h fh[2][4];
#pragma unroll
    for (int arr = 0; arr < 2; ++arr) {
        const float* P = arr ? ii : ir;
        const int b = vox_w + vh * 32 + col;
#pragma unroll
        for (int ks = 0; ks < 4; ++ks) {
            v8h H;
#pragma unroll
            for (int j = 0; j < 8; ++j) {
                const int k = ks * 16 + hk * 8 + j;
                H[j] = (_Float16)P[k * B_VOX + b];
            }
            fh[arr][ks] = H;
        }
    }

    // ---- y A-frags: [ri][ks], n = nh*32+col, q = ks*2+hk ----
    v8h yf[2][4];
    auto loadf = [&](int T) {
        const v8h* yv = (const v8h*)((const char*)yp + (size_t)T * 16384);
        const int nr = nh * 32 + col;
#pragma unroll
        for (int ri = 0; ri < 2; ++ri)
#pragma unroll
            for (int ks = 0; ks < 4; ++ks)
                yf[ri][ks] = yv[(ri * 8 + ks * 2 + hk) * 64 + nr];
    };

    const v16f zc16 = {0.f,0.f,0.f,0.f,0.f,0.f,0.f,0.f,
                       0.f,0.f,0.f,0.f,0.f,0.f,0.f,0.f};
    unsigned t2a[4] = {0u,0u,0u,0u}, t2b[4] = {0u,0u,0u,0u};

    loadf(T0);
    for (int T = T0; T < T1; ++T) {
        const int tl = T - T0;
        v16f acc0, acc1, acc2, acc3;        // yr*ir, yi*ir, yr*ii, yi*ii
#define MF(A, B, C) __builtin_amdgcn_mfma_f32_32x32x16_f16(A, B, C, 0, 0, 0)
        acc0 = MF(yf[0][0], fh[0][0], zc16);
        acc1 = MF(yf[1][0], fh[0][0], zc16);
        acc2 = MF(yf[0][0], fh[1][0], zc16);
        acc3 = MF(yf[1][0], fh[1][0], zc16);
#pragma unroll
        for (int ks = 1; ks < 4; ++ks) {
            acc0 = MF(yf[0][ks], fh[0][ks], acc0);
            acc1 = MF(yf[1][ks], fh[0][ks], acc1);
            acc2 = MF(yf[0][ks], fh[1][ks], acc2);
            acc3 = MF(yf[1][ks], fh[1][ks], acc3);
        }
#undef MF
        // yf dead; issue next-tile loads so the epilogue runs under latency
        if (T + 1 < T1) loadf(T + 1);

        // ---- sim + top-2: packed-f32 sim, med3 second-best, 4 chains ----
        // row(reg) = (reg&3) + 8*(reg>>2) + 4*hk ; n = T*64 + nh*32 + row
        const unsigned invb = 0x1FFFu
            - (unsigned)(tl * 64 + nh * 32 + hk * 4);
#define EPI(G) { \
        const unsigned baseg = invb - (unsigned)(8 * G); \
        v2f s01, s23; \
        { v2f p0 = __builtin_shufflevector(acc0, acc0, 4*G+0, 4*G+1); \
          v2f p1 = __builtin_shufflevector(acc1, acc1, 4*G+0, 4*G+1); \
          v2f p2 = __builtin_shufflevector(acc2, acc2, 4*G+0, 4*G+1); \
          v2f p3 = __builtin_shufflevector(acc3, acc3, 4*G+0, 4*G+1); \
          v2f s = p0 * p0; \
          s = __builtin_elementwise_fma(p1, p1, s); \
          s = __builtin_elementwise_fma(p2, p2, s); \
          s = __builtin_elementwise_fma(p3, p3, s); \
          s01 = s; } \
        { v2f p0 = __builtin_shufflevector(acc0, acc0, 4*G+2, 4*G+3); \
          v2f p1 = __builtin_shufflevector(acc1, acc1, 4*G+2, 4*G+3); \
          v2f p2 = __builtin_shufflevector(acc2, acc2, 4*G+2, 4*G+3); \
          v2f p3 = __builtin_shufflevector(acc3, acc3, 4*G+2, 4*G+3); \
          v2f s = p0 * p0; \
          s = __builtin_elementwise_fma(p1, p1, s); \
          s = __builtin_elementwise_fma(p2, p2, s); \
          s = __builtin_elementwise_fma(p3, p3, s); \
          s23 = s; } \
        _Pragma("unroll") \
        for (int r = 0; r < 4; ++r) { \
            const float sv = (r < 2) ? s01[r] : s23[r - 2]; \
            const unsigned pb = (__float_as_uint(sv) & 0xFFFFE000u) \
                              | (baseg - (unsigned)r); \
            t2b[G] = umed3(pb, t2a[G], t2b[G]); \
            t2a[G] = umax32(pb, t2a[G]); } }
        EPI(0) EPI(1) EPI(2) EPI(3)
#undef EPI
    }

    // ---- merge 4 chains (per lane) ----
    unsigned a1 = t2a[0], a2 = t2b[0];
#pragma unroll
    for (int g = 1; g < 4; ++g) {
        unsigned lo = umin32(a1, t2a[g]);
        a1 = umax32(a1, t2a[g]);
        a2 = umax32(umax32(a2, t2b[g]), lo);
    }
    // ---- merge hk halves: lane c <-> c+32 hold same vox, disjoint rows ----
    {
        unsigned b1 = (unsigned)__shfl_xor((int)a1, 32, 64);
        unsigned b2 = (unsigned)__shfl_xor((int)a2, 32, 64);
        unsigned mn = umin32(a1, b1);
        a1 = umax32(a1, b1);
        a2 = umax32(mn, umax32(a2, b2));
    }
    // ---- cross-wave (nh) merge: nh==1 publishes, nh==0 writes ----
    if (nh == 1 && lane < 32) { xm[vh][lane][0] = a1; xm[vh][lane][1] = a2; }
    __syncthreads();
    if (nh == 0 && lane < 32) {
        const unsigned b1 = xm[vh][lane][0];
        const unsigned b2 = xm[vh][lane][1];
        const unsigned m1 = umax32(a1, b1);
        const unsigned m2 = umax32(umin32(a1, b1), umax32(a2, b2));
        const size_t vox = vox_w + vh * 32 + lane;
        cand[vox * slots + chunk * 2 + 0] = m1;
        cand[vox * slots + chunk * 2 + 1] = m2;
    }
}

// ---------------------------------------------------------------------------
// Phase B (fused): exact fp32 rescore of candidates within 3% of approx max,
// winner lane computes scales and writes the 4 output rows directly.
// One wave per voxel.
// ---------------------------------------------------------------------------
__global__ __launch_bounds__(256) void rescore_finish(
    const float* __restrict__ ir, const float* __restrict__ ii,
    const float* __restrict__ yr, const float* __restrict__ yi,
    const float* __restrict__ inv, const float* __restrict__ x1,
    const float* __restrict__ x2,
    const unsigned* __restrict__ cand, int slots, int tpc,
    float* __restrict__ out)
{
    const int tid  = threadIdx.x;
    const int vox  = blockIdx.x * 4 + (tid >> 6);
    const int slot = tid & 63;

    unsigned p = (slot < slots) ? cand[(size_t)vox * slots + slot] : 0u;
    float sa = __uint_as_float(p & 0xFFFFE000u);
    const int chunkc = slot >> 1;
    const int nn = chunkc * tpc * 64 + (0x1FFF - (int)(p & 0x1FFFu));

    float amax = sa;
#pragma unroll
    for (int d = 1; d <= 32; d <<= 1) amax = fmaxf(amax, __shfl_xor(amax, d, 64));

    unsigned long long q = 0ull;
    float rr = 0.f, ri = 0.f, s1 = 0.f, s2 = 0.f;
    const bool active = (slot < slots) && (nn >= 0) && (nn < N_DICT)
                     && (sa >= 0.97f * amax);    // margin covers 1-term f16 error
    if (active) {
        for (int m = 0; m < M_TIME; ++m) {
            float a  = yr[(size_t)m * N_DICT + nn];
            float c  = yi[(size_t)m * N_DICT + nn];
            float vr = ir[m * B_VOX + vox];
            float vi = ii[m * B_VOX + vox];
            rr = fmaf(vr, a, rr); ri = fmaf(vr, c, ri);
            s1 = fmaf(vi, a, s1); s2 = fmaf(vi, c, s2);
        }
        float s = fmaf(rr, rr, fmaf(ri, ri, fmaf(s1, s1, s2 * s2)));
        q = (((unsigned long long)__float_as_uint(s)) << 32)
          | (unsigned long long)(0xFFFFFFFFu - (unsigned)nn);  // ties -> smaller n
    }
    unsigned long long qm = q;
#pragma unroll
    for (int d = 1; d <= 32; d <<= 1) qm = u64max(qm, __shfl_xor(qm, d, 64));

    if (active && q == qm && qm != 0ull) {       // exactly one lane (n in key)
        float ss = inv[nn];
        out[0 * B_VOX + vox] = (rr + s2) * ss;   // sum(yr*ir + yi*ii) * inv
        out[1 * B_VOX + vox] = (s1 - ri) * ss;   // sum(yr*ii - yi*ir) * inv
        out[2 * B_VOX + vox] = x1[nn];
        out[3 * B_VOX + vox] = x2[nn];
    }
}

// ---------------------------------------------------------------------------
// Last-resort fallbacks (tiny ws): fp32 brute-force argmax + finish.
// ---------------------------------------------------------------------------
__global__ __launch_bounds__(256, 3) void argmax_naive(
    const float* __restrict__ ir, const float* __restrict__ ii,
    const float* __restrict__ yr, const float* __restrict__ yi,
    int* __restrict__ idxout)
{
    int b = blockIdx.x * 256 + threadIdx.x;
    float bs = -1.0f; int bn = 0;
    for (int n = 0; n < N_DICT; ++n) {
        float a_rr = 0.f, a_ri = 0.f, a_s1 = 0.f, a_s2 = 0.f;
        for (int m = 0; m < M_TIME; ++m) {
            float a = yr[m * N_DICT + n], c = yi[m * N_DICT + n];
            float vr = ir[m * B_VOX + b], vi = ii[m * B_VOX + b];
            a_rr = fmaf(vr, a, a_rr); a_ri = fmaf(vr, c, a_ri);
            a_s1 = fmaf(vi, a, a_s1); a_s2 = fmaf(vi, c, a_s2);
        }
        float sim = fmaf(a_rr, a_rr, fmaf(a_ri, a_ri, fmaf(a_s1, a_s1, a_s2 * a_s2)));
        if (sim > bs) { bs = sim; bn = n; }
    }
    idxout[b] = bn;
}

__global__ void finish_k(const float* __restrict__ ir, const float* __restrict__ ii,
                         const float* __restrict__ yr, const float* __restrict__ yi,
                         const float* __restrict__ inv, const float* __restrict__ x1,
                         const float* __restrict__ x2,
                         const int* __restrict__ idxin, float* __restrict__ out)
{
    int b = blockIdx.x * blockDim.x + threadIdx.x;
    int idx = idxin[b];
    float ar = 0.f, ai = 0.f;
    for (int m = 0; m < M_TIME; ++m) {
        float a  = yr[(size_t)m * N_DICT + idx];
        float c  = yi[(size_t)m * N_DICT + idx];
        float vr = ir[m * B_VOX + b];
        float vi = ii[m * B_VOX + b];
        ar = fmaf(a, vr, ar); ar = fmaf(c, vi, ar);
        ai = fmaf(a, vi, ai); ai = fmaf(-c, vr, ai);
    }
    float s = inv[idx];
    out[0 * B_VOX + b] = ar * s;
    out[1 * B_VOX + b] = ai * s;
    out[2 * B_VOX + b] = x1[idx];
    out[3 * B_VOX + b] = x2[idx];
}

extern "C" void kernel_launch(void* const* d_in, const int* in_sizes, int n_in,
                              void* d_out, int out_size, void* d_ws, size_t ws_size,
                              hipStream_t stream) {
    const float* ir  = (const float*)d_in[0];
    const float* ii  = (const float*)d_in[1];
    const float* yr  = (const float*)d_in[2];
    const float* yi  = (const float*)d_in[3];
    const float* inv = (const float*)d_in[4];
    const float* x1  = (const float*)d_in[5];
    const float* x2  = (const float*)d_in[6];
    float* out = (float*)d_out;

    const size_t yp_bytes = (size_t)NTILES * 16384;    // 5.13 MB (f16 frag tiles)

    // pick largest chunk count whose cand buffer fits alongside yp (slots <= 64)
    int CH = 0;
    for (int c = 32; c >= 4; c >>= 1) {
        size_t cand_bytes = (size_t)B_VOX * (2 * c) * sizeof(unsigned);
        if (ws_size >= cand_bytes + yp_bytes) { CH = c; break; }
    }

    if (CH > 0) {
        const int slots = 2 * CH;
        const int tpc   = (NTILES + CH - 1) / CH;
        unsigned* cand = (unsigned*)d_ws;
        v8h* yp = (v8h*)((char*)d_ws + (size_t)B_VOX * slots * sizeof(unsigned));

        const int units = 2 * NTILES * 512;
        split_y<<<(units + 255) / 256, 256, 0, stream>>>(yr, yi, yp);
        gemm_pre<<<dim3(B_VOX / 64, CH), 256, 0, stream>>>(ir, ii, yp, cand, tpc, slots);
        rescore_finish<<<B_VOX / 4, 256, 0, stream>>>(ir, ii, yr, yi, inv, x1, x2,
                                                      cand, slots, tpc, out);
    } else {
        int* idxo = (int*)(out + 3 * B_VOX);   // alias out row 3 (read-before-write)
        argmax_naive<<<B_VOX / 256, 256, 0, stream>>>(ir, ii, yr, yi, idxo);
        finish_k<<<B_VOX / 256, 256, 0, stream>>>(ir, ii, yr, yi,
                                                  inv, x1, x2, idxo, out);
    }
}

// Round 11
// 189.673 us; speedup vs baseline: 1.1033x; 1.1033x over previous
//
#include <hip/hip_runtime.h>
#include <hip/hip_bf16.h>
#include <stdint.h>

#define M_TIME 64
#define N_DICT 20000
#define B_VOX  8192

#define NTILES 313    // ceil(20000/64); last tile padded with zeros

typedef _Float16 v8h __attribute__((ext_vector_type(8)));   // 8 f16 (4 VGPRs)
typedef float    v4f __attribute__((ext_vector_type(4)));
typedef float    v2f __attribute__((ext_vector_type(2)));

__device__ __forceinline__ unsigned long long u64max(unsigned long long a, unsigned long long b) { return a > b ? a : b; }
__device__ __forceinline__ unsigned umin32(unsigned a, unsigned b) { return a < b ? a : b; }
__device__ __forceinline__ unsigned umax32(unsigned a, unsigned b) { return a > b ? a : b; }
// median of 3 == second-largest of 3: one VOP3 op (pure reg computation).
__device__ __forceinline__ unsigned umed3(unsigned a, unsigned b, unsigned c) {
    unsigned d;
    asm("v_med3_u32 %0, %1, %2, %3" : "=v"(d) : "v"(a), "v"(b), "v"(c));
    return d;
}

// ---------------------------------------------------------------------------
// Prepass: convert y to f16 ONCE, packed in A-fragment order.
// Tile T = 16 fragment-rows fr = (arr*2 + h)*4 + quad; row = 64 n x 8 f16
// (k = h*32 + quad*8 + j). 16 KB/tile.
// ---------------------------------------------------------------------------
__global__ __launch_bounds__(256) void split_y(
    const float* __restrict__ yr, const float* __restrict__ yi,
    v8h* __restrict__ yp)
{
    const int u = blockIdx.x * 256 + threadIdx.x;   // [arr][T][j(8)][n_l(64)]
    const int n_l = u & 63;
    const int j   = (u >> 6) & 7;       // fragment sub-row: k = j*8 .. j*8+7
    const int T   = (u >> 9) % NTILES;
    const int arr = u / (NTILES * 512);
    if (arr > 1) return;
    const float* P = arr ? yi : yr;
    const int n_g = T * 64 + n_l;
    v8h V;
#pragma unroll
    for (int c = 0; c < 8; ++c) {
        float v = 0.f;
        if (n_g < N_DICT) v = P[(j * 8 + c) * N_DICT + n_g];
        V[c] = (_Float16)v;
    }
    const int fr = (arr * 2 + (j >> 2)) * 4 + (j & 3);   // h = j>>2, quad = j&3
    yp[((size_t)T * 16 + fr) * 64 + n_l] = V;
}

// ---------------------------------------------------------------------------
// R26: fp32 transposed dictionary yt[n][m] = {yr[m][n], yi[m][n]}.
// Rescore candidate gather: 128 scattered 64B lines (two 80KB-stride
// column walks) -> 8 contiguous lines (512 B). Runs AFTER gemm_pre and
// overwrites the then-dead yp region (ws needs cand + max(yp,yt) only).
// Rationale: with random data the 32 chunk-maxima are near-iid max-of-625
// samples -> they cluster within a few % -> MANY lanes pass the 0.97
// threshold -> rescore's gather may be the never-measured ~95 us residue.
// R18/R20's "yt null" was an unexecuted experiment (mode likely never
// activated for ws < 12.3 MB; no counter visibility) - this cascade
// activates for any ws >= ~10.8 MB.
// ---------------------------------------------------------------------------
__global__ __launch_bounds__(256) void trans_y(
    const float* __restrict__ yr, const float* __restrict__ yi,
    float2* __restrict__ yt)
{
    __shared__ float tr[64][65];
    __shared__ float ti[64][65];
    const int t  = threadIdx.x;
    const int n0 = blockIdx.x * 64;
    const int nl = t & 63;
    const int mg = t >> 6;                    // 0..3 (16 m-rows each)
    const bool inb = (n0 + nl) < N_DICT;
#pragma unroll
    for (int i = 0; i < 16; ++i) {
        const int m = mg * 16 + i;
        tr[m][nl] = inb ? yr[m * N_DICT + n0 + nl] : 0.f;
        ti[m][nl] = inb ? yi[m * N_DICT + n0 + nl] : 0.f;
    }
    __syncthreads();
    const int nw = t >> 2;                    // 0..63
    const int j  = t & 3;                     // 0..3 (16 m each)
    if (n0 + nw < N_DICT) {
        float4* dst = (float4*)(yt + (size_t)(n0 + nw) * 64);
#pragma unroll
        for (int k = 0; k < 8; ++k) {
            const int m = j * 16 + 2 * k;
            float4 w;
            w.x = tr[m][nw];     w.y = ti[m][nw];
            w.z = tr[m + 1][nw]; w.w = ti[m + 1][nw];
            dst[j * 8 + k] = w;               // element pair m/2
        }
    }
}

// ---------------------------------------------------------------------------
// Phase A: f16 1-term MFMA GEMM + per-chunk top-2. == R24 VERBATIM ==
// (87.4 us, MfmaUtil 43% = 965 TF = the documented plain-HIP 2-barrier
// structure ceiling, m97 ladder. MFMA-pipe busy time is ~38 us = the pipe
// floor in EVERY variant tried: barrier (R21), order (R22), occupancy
// (R20/22), latency depth (R23), L1 traffic (R24), MFMA shape (R25,
// REVERTED: -33 us, halved chains + re-doubled frag traffic). Breaking
// past needs the 8-phase T2-T5 combo rewrite; this round targets the
// never-measured ~95 us non-gemm residue instead, gemm kept frozen for
// attribution.)
// ---------------------------------------------------------------------------
__global__ __launch_bounds__(256, 2) void gemm_pre(
    const float* __restrict__ ir, const float* __restrict__ ii,
    const v8h* __restrict__ yp,
    unsigned* __restrict__ cand, int tpc, int slots)
{
    __shared__ unsigned xm[4][4][16][2];    // [wave][bt][col][a1,a2]  2 KB

    const int tid  = threadIdx.x;
    const int wave = tid >> 6, lane = tid & 63;
    const int quad = lane >> 4, col = lane & 15;
    const int vox_w = blockIdx.x * 64;      // all 4 waves share the 64 voxels
    const int chunk = blockIdx.y;
    const int T0 = chunk * tpc;
    const int T1 = (T0 + tpc < NTILES) ? T0 + tpc : NTILES;

    // ---- persistent input B-frags: [arr][bt][h], bt = 0..3 (16 v8h) ----
    v8h fh[2][4][2];
#pragma unroll
    for (int arr = 0; arr < 2; ++arr) {
        const float* P = arr ? ii : ir;
#pragma unroll
        for (int bt = 0; bt < 4; ++bt) {
            const int b = vox_w + bt * 16 + col;
#pragma unroll
            for (int h = 0; h < 2; ++h) {
                v8h H;
#pragma unroll
                for (int j = 0; j < 8; ++j) {
                    const int k = h * 32 + quad * 8 + j;
                    H[j] = (_Float16)P[k * B_VOX + b];
                }
                fh[arr][bt][h] = H;
            }
        }
    }

    // ---- y A-frags: [ri][h], nrow = wave*16+col (4 v8h = 4 KB/tile) ----
    v8h yf[2][2];
    auto loadf = [&](int T) {
        const v8h* yv = (const v8h*)((const char*)yp + (size_t)T * 16384);
        const int nrow = wave * 16 + col;
#pragma unroll
        for (int ri = 0; ri < 2; ++ri)
#pragma unroll
            for (int h = 0; h < 2; ++h)
                yf[ri][h] = yv[((ri * 2 + h) * 4 + quad) * 64 + nrow];
    };

    const v4f zc = {0.f, 0.f, 0.f, 0.f};
    unsigned t2a[4] = {0u, 0u, 0u, 0u}, t2b[4] = {0u, 0u, 0u, 0u};

    loadf(T0);
    for (int T = T0; T < T1; ++T) {
        const int tl = T - T0;
        v4f acc[4][4];                      // [bt][rr,ri,s1,s2]
#define MF(A, B, C) __builtin_amdgcn_mfma_f32_16x16x32_f16(A, B, C, 0, 0, 0)
#pragma unroll
        for (int bt = 0; bt < 4; ++bt) {
            acc[bt][0] = MF(yf[0][0], fh[0][bt][0], zc);
            acc[bt][1] = MF(yf[1][0], fh[0][bt][0], zc);
            acc[bt][2] = MF(yf[0][0], fh[1][bt][0], zc);
            acc[bt][3] = MF(yf[1][0], fh[1][bt][0], zc);
        }
#pragma unroll
        for (int bt = 0; bt < 4; ++bt) {
            acc[bt][0] = MF(yf[0][1], fh[0][bt][1], acc[bt][0]);
            acc[bt][1] = MF(yf[1][1], fh[0][bt][1], acc[bt][1]);
            acc[bt][2] = MF(yf[0][1], fh[1][bt][1], acc[bt][2]);
            acc[bt][3] = MF(yf[1][1], fh[1][bt][1], acc[bt][3]);
        }
#undef MF
        // yf dead; issue next-tile loads so the epilogue runs under latency
        if (T + 1 < T1) loadf(T + 1);

        // ---- sim + top-2: packed-f32 sim, med3 second-best ----
        const unsigned base = 0x1FFFu
            - (unsigned)(tl * 64 + wave * 16 + quad * 4);
#pragma unroll
        for (int bt = 0; bt < 4; ++bt) {
            v2f s01, s23;
            {
                const v2f p0 = __builtin_shufflevector(acc[bt][0], acc[bt][0], 0, 1);
                const v2f p1 = __builtin_shufflevector(acc[bt][1], acc[bt][1], 0, 1);
                const v2f p2 = __builtin_shufflevector(acc[bt][2], acc[bt][2], 0, 1);
                const v2f p3 = __builtin_shufflevector(acc[bt][3], acc[bt][3], 0, 1);
                v2f s = p0 * p0;
                s = __builtin_elementwise_fma(p1, p1, s);
                s = __builtin_elementwise_fma(p2, p2, s);
                s = __builtin_elementwise_fma(p3, p3, s);
                s01 = s;
            }
            {
                const v2f p0 = __builtin_shufflevector(acc[bt][0], acc[bt][0], 2, 3);
                const v2f p1 = __builtin_shufflevector(acc[bt][1], acc[bt][1], 2, 3);
                const v2f p2 = __builtin_shufflevector(acc[bt][2], acc[bt][2], 2, 3);
                const v2f p3 = __builtin_shufflevector(acc[bt][3], acc[bt][3], 2, 3);
                v2f s = p0 * p0;
                s = __builtin_elementwise_fma(p1, p1, s);
                s = __builtin_elementwise_fma(p2, p2, s);
                s = __builtin_elementwise_fma(p3, p3, s);
                s23 = s;
            }
#pragma unroll
            for (int r = 0; r < 4; ++r) {       // 4 independent bt chains
                const float s = (r < 2) ? s01[r] : s23[r - 2];
                const unsigned pb = (__float_as_uint(s) & 0xFFFFE000u)
                                  | (base - (unsigned)r);
                const unsigned nb = umed3(pb, t2a[bt], t2b[bt]);  // 2nd-best
                t2a[bt] = umax32(pb, t2a[bt]);
                t2b[bt] = nb;
            }
        }
    }

    // ---- cross-lane top-2 merge over quads (lanes c, c+16, c+32, c+48) ----
    unsigned fa1[4], fa2[4];
#pragma unroll
    for (int bt = 0; bt < 4; ++bt) {
        unsigned a1 = t2a[bt], a2 = t2b[bt];
#pragma unroll
        for (int d = 16; d <= 32; d <<= 1) {
            unsigned b1 = (unsigned)__shfl_xor((int)a1, d, 64);
            unsigned b2 = (unsigned)__shfl_xor((int)a2, d, 64);
            unsigned mn = umin32(a1, b1);
            a1 = umax32(a1, b1);
            a2 = umax32(mn, umax32(a2, b2));
        }
        fa1[bt] = a1; fa2[bt] = a2;
    }
    // ---- cross-wave merge: all 4 waves publish, wave 0 merges 4-way ----
    if (lane < 16) {
#pragma unroll
        for (int bt = 0; bt < 4; ++bt) {
            xm[wave][bt][lane][0] = fa1[bt];
            xm[wave][bt][lane][1] = fa2[bt];
        }
    }
    __syncthreads();
    if (wave == 0 && lane < 16) {
#pragma unroll
        for (int bt = 0; bt < 4; ++bt) {
            unsigned m1 = 0u, m2 = 0u;
#pragma unroll
            for (int w = 0; w < 4; ++w) {
                const unsigned b1 = xm[w][bt][lane][0];
                const unsigned b2 = xm[w][bt][lane][1];
                m2 = umax32(m2, umax32(b2, umin32(m1, b1)));
                m1 = umax32(m1, b1);
            }
            const size_t vox = vox_w + bt * 16 + lane;
            cand[vox * slots + chunk * 2 + 0] = m1;
            cand[vox * slots + chunk * 2 + 1] = m2;
        }
    }
}

// ---------------------------------------------------------------------------
// Phase B (fused): exact fp32 rescore of candidates within 3% of approx max,
// winner lane computes scales and writes the 4 output rows directly.
// One wave per voxel. yt path: 8 contiguous lines per candidate instead of
// 128 scattered ones; ir/ii reads are wave-uniform (vox fixed per wave).
// ---------------------------------------------------------------------------
__global__ __launch_bounds__(256) void rescore_finish(
    const float* __restrict__ ir, const float* __restrict__ ii,
    const float* __restrict__ yr, const float* __restrict__ yi,
    const float2* __restrict__ yt,
    const float* __restrict__ inv, const float* __restrict__ x1,
    const float* __restrict__ x2,
    const unsigned* __restrict__ cand, int slots, int tpc,
    float* __restrict__ out)
{
    const int tid  = threadIdx.x;
    const int vox  = blockIdx.x * 4 + (tid >> 6);
    const int slot = tid & 63;

    unsigned p = (slot < slots) ? cand[(size_t)vox * slots + slot] : 0u;
    float sa = __uint_as_float(p & 0xFFFFE000u);
    const int chunkc = slot >> 1;
    const int nn = chunkc * tpc * 64 + (0x1FFF - (int)(p & 0x1FFFu));

    float amax = sa;
#pragma unroll
    for (int d = 1; d <= 32; d <<= 1) amax = fmaxf(amax, __shfl_xor(amax, d, 64));

    unsigned long long q = 0ull;
    float rr = 0.f, ri = 0.f, s1 = 0.f, s2 = 0.f;
    const bool active = (slot < slots) && (nn >= 0) && (nn < N_DICT)
                     && (sa >= 0.97f * amax);    // margin covers 1-term f16 error
    if (active) {
        if (yt) {
            const float4* yc = (const float4*)(yt + (size_t)nn * 64);
            for (int m2 = 0; m2 < 32; ++m2) {
                const float4 w = yc[m2];               // {yr,yi}[2m], {yr,yi}[2m+1]
                const int m = 2 * m2;
                float vr0 = ir[m * B_VOX + vox],       vi0 = ii[m * B_VOX + vox];
                float vr1 = ir[(m + 1) * B_VOX + vox], vi1 = ii[(m + 1) * B_VOX + vox];
                rr = fmaf(vr0, w.x, rr); ri = fmaf(vr0, w.y, ri);
                s1 = fmaf(vi0, w.x, s1); s2 = fmaf(vi0, w.y, s2);
                rr = fmaf(vr1, w.z, rr); ri = fmaf(vr1, w.w, ri);
                s1 = fmaf(vi1, w.z, s1); s2 = fmaf(vi1, w.w, s2);
            }
        } else {
            for (int m = 0; m < M_TIME; ++m) {
                float a  = yr[(size_t)m * N_DICT + nn];
                float c  = yi[(size_t)m * N_DICT + nn];
                float vr = ir[m * B_VOX + vox];
                float vi = ii[m * B_VOX + vox];
                rr = fmaf(vr, a, rr); ri = fmaf(vr, c, ri);
                s1 = fmaf(vi, a, s1); s2 = fmaf(vi, c, s2);
            }
        }
        float s = fmaf(rr, rr, fmaf(ri, ri, fmaf(s1, s1, s2 * s2)));
        q = (((unsigned long long)__float_as_uint(s)) << 32)
          | (unsigned long long)(0xFFFFFFFFu - (unsigned)nn);  // ties -> smaller n
    }
    unsigned long long qm = q;
#pragma unroll
    for (int d = 1; d <= 32; d <<= 1) qm = u64max(qm, __shfl_xor(qm, d, 64));

    if (active && q == qm && qm != 0ull) {       // exactly one lane (n in key)
        float ss = inv[nn];
        out[0 * B_VOX + vox] = (rr + s2) * ss;   // sum(yr*ir + yi*ii) * inv
        out[1 * B_VOX + vox] = (s1 - ri) * ss;   // sum(yr*ii - yi*ir) * inv
        out[2 * B_VOX + vox] = x1[nn];
        out[3 * B_VOX + vox] = x2[nn];
    }
}

// ---------------------------------------------------------------------------
// Last-resort fallbacks (tiny ws): fp32 brute-force argmax + finish.
// ---------------------------------------------------------------------------
__global__ __launch_bounds__(256, 3) void argmax_naive(
    const float* __restrict__ ir, const float* __restrict__ ii,
    const float* __restrict__ yr, const float* __restrict__ yi,
    int* __restrict__ idxout)
{
    int b = blockIdx.x * 256 + threadIdx.x;
    float bs = -1.0f; int bn = 0;
    for (int n = 0; n < N_DICT; ++n) {
        float a_rr = 0.f, a_ri = 0.f, a_s1 = 0.f, a_s2 = 0.f;
        for (int m = 0; m < M_TIME; ++m) {
            float a = yr[m * N_DICT + n], c = yi[m * N_DICT + n];
            float vr = ir[m * B_VOX + b], vi = ii[m * B_VOX + b];
            a_rr = fmaf(vr, a, a_rr); a_ri = fmaf(vr, c, a_ri);
            a_s1 = fmaf(vi, a, a_s1); a_s2 = fmaf(vi, c, a_s2);
        }
        float sim = fmaf(a_rr, a_rr, fmaf(a_ri, a_ri, fmaf(a_s1, a_s1, a_s2 * a_s2)));
        if (sim > bs) { bs = sim; bn = n; }
    }
    idxout[b] = bn;
}

__global__ void finish_k(const float* __restrict__ ir, const float* __restrict__ ii,
                         const float* __restrict__ yr, const float* __restrict__ yi,
                         const float* __restrict__ inv, const float* __restrict__ x1,
                         const float* __restrict__ x2,
                         const int* __restrict__ idxin, float* __restrict__ out)
{
    int b = blockIdx.x * blockDim.x + threadIdx.x;
    int idx = idxin[b];
    float ar = 0.f, ai = 0.f;
    for (int m = 0; m < M_TIME; ++m) {
        float a  = yr[(size_t)m * N_DICT + idx];
        float c  = yi[(size_t)m * N_DICT + idx];
        float vr = ir[m * B_VOX + b];
        float vi = ii[m * B_VOX + b];
        ar = fmaf(a, vr, ar); ar = fmaf(c, vi, ar);
        ai = fmaf(a, vi, ai); ai = fmaf(-c, vr, ai);
    }
    float s = inv[idx];
    out[0 * B_VOX + b] = ar * s;
    out[1 * B_VOX + b] = ai * s;
    out[2 * B_VOX + b] = x1[idx];
    out[3 * B_VOX + b] = x2[idx];
}

extern "C" void kernel_launch(void* const* d_in, const int* in_sizes, int n_in,
                              void* d_out, int out_size, void* d_ws, size_t ws_size,
                              hipStream_t stream) {
    const float* ir  = (const float*)d_in[0];
    const float* ii  = (const float*)d_in[1];
    const float* yr  = (const float*)d_in[2];
    const float* yi  = (const float*)d_in[3];
    const float* inv = (const float*)d_in[4];
    const float* x1  = (const float*)d_in[5];
    const float* x2  = (const float*)d_in[6];
    float* out = (float*)d_out;

    const size_t yp_bytes = (size_t)NTILES * 16384;               // 5.13 MB
    const size_t yt_bytes = (size_t)N_DICT * 64 * sizeof(float2); // 10.24 MB
    const size_t ov_bytes = yt_bytes > yp_bytes ? yt_bytes : yp_bytes;

    // Cascade: prefer largest CH with the yt overlap region (trans_y runs
    // AFTER gemm and overwrites the dead yp); fall back to no-yt mode 0.
    int CH = 0; bool use_yt = false;
    for (int c = 32; c >= 8 && CH == 0; c >>= 1) {
        size_t cb = (size_t)B_VOX * (2 * c) * sizeof(unsigned);
        if (ws_size >= cb + ov_bytes) { CH = c; use_yt = true; }
    }
    for (int c = 32; c >= 4 && CH == 0; c >>= 1) {
        size_t cb = (size_t)B_VOX * (2 * c) * sizeof(unsigned);
        if (ws_size >= cb + yp_bytes) { CH = c; }
    }

    if (CH > 0) {
        const int slots = 2 * CH;
        const int tpc   = (NTILES + CH - 1) / CH;
        unsigned* cand = (unsigned*)d_ws;
        char* base = (char*)d_ws + (size_t)B_VOX * slots * sizeof(unsigned);
        v8h*    yp = (v8h*)base;
        float2* yt = use_yt ? (float2*)base : nullptr;   // overlaps yp (post-gemm)

        const int units = 2 * NTILES * 512;
        split_y<<<(units + 255) / 256, 256, 0, stream>>>(yr, yi, yp);
        gemm_pre<<<dim3(B_VOX / 64, CH), 256, 0, stream>>>(ir, ii, yp, cand, tpc, slots);
        if (use_yt) trans_y<<<NTILES, 256, 0, stream>>>(yr, yi, yt);
        rescore_finish<<<B_VOX / 4, 256, 0, stream>>>(ir, ii, yr, yi, yt, inv, x1, x2,
                                                      cand, slots, tpc, out);
    } else {
        int* idxo = (int*)(out + 3 * B_VOX);   // alias out row 3 (read-before-write)
        argmax_naive<<<B_VOX / 256, 256, 0, stream>>>(ir, ii, yr, yi, idxo);
        finish_k<<<B_VOX / 256, 256, 0, stream>>>(ir, ii, yr, yi,
                                                  inv, x1, x2, idxo, out);
    }
}

// Round 14
// 188.315 us; speedup vs baseline: 1.1112x; 1.0072x over previous
//
#include <hip/hip_runtime.h>
#include <hip/hip_bf16.h>
#include <stdint.h>

#define M_TIME 64
#define N_DICT 20000
#define B_VOX  8192

#define NTILES 313    // ceil(20000/64); last tile padded with zeros

typedef _Float16 v8h __attribute__((ext_vector_type(8)));   // 8 f16 (4 VGPRs)
typedef float    v4f __attribute__((ext_vector_type(4)));
typedef float    v2f __attribute__((ext_vector_type(2)));

__device__ __forceinline__ unsigned long long u64max(unsigned long long a, unsigned long long b) { return a > b ? a : b; }
__device__ __forceinline__ unsigned umin32(unsigned a, unsigned b) { return a < b ? a : b; }
__device__ __forceinline__ unsigned umax32(unsigned a, unsigned b) { return a > b ? a : b; }
// median of 3 == second-largest of 3: one VOP3 op (pure reg computation).
__device__ __forceinline__ unsigned umed3(unsigned a, unsigned b, unsigned c) {
    unsigned d;
    asm("v_med3_u32 %0, %1, %2, %3" : "=v"(d) : "v"(a), "v"(b), "v"(c));
    return d;
}

// ---------------------------------------------------------------------------
// Prepass: convert y to f16 ONCE, packed in A-fragment order.
// Tile T = 16 fragment-rows fr = (arr*2 + h)*4 + quad; row = 64 n x 8 f16
// (k = h*32 + quad*8 + j). 16 KB/tile.
// ---------------------------------------------------------------------------
__global__ __launch_bounds__(256) void split_y(
    const float* __restrict__ yr, const float* __restrict__ yi,
    v8h* __restrict__ yp)
{
    const int u = blockIdx.x * 256 + threadIdx.x;   // [arr][T][j(8)][n_l(64)]
    const int n_l = u & 63;
    const int j   = (u >> 6) & 7;       // fragment sub-row: k = j*8 .. j*8+7
    const int T   = (u >> 9) % NTILES;
    const int arr = u / (NTILES * 512);
    if (arr > 1) return;
    const float* P = arr ? yi : yr;
    const int n_g = T * 64 + n_l;
    v8h V;
#pragma unroll
    for (int c = 0; c < 8; ++c) {
        float v = 0.f;
        if (n_g < N_DICT) v = P[(j * 8 + c) * N_DICT + n_g];
        V[c] = (_Float16)v;
    }
    const int fr = (arr * 2 + (j >> 2)) * 4 + (j & 3);   // h = j>>2, quad = j&3
    yp[((size_t)T * 16 + fr) * 64 + n_l] = V;
}

// ---------------------------------------------------------------------------
// Phase A: f16 1-term MFMA GEMM + per-chunk top-2 (u32 packed comparator).
// == R24 structure (measured clean in R9: 87.4 us, MfmaUtil 43) plus ONE
// change: chunk-per-XCD block swizzle. ==
// Stall model: per tile-period ~3340 cyc = 1428 MFMA-pipe + ~180 true-VALU
// + ~1700 idle (~830 cyc/wave load stall = L3-class latency). Cause: yp
// tiles read by 128 blocks spread over all 8 XCDs -> per-XCD L2 must hold
// all 32 chunks (5.1 MB > 4 MB) -> tiles served from L3 (~500-900 cyc).
// Swizzle: linear block id % 8 selects XCD on MI355X (m09); remap so all
// 128 blocks of a chunk land on ONE XCD -> per-XCD yp footprint 640 KB,
// L2-resident (~200 cyc), hidden by TLP + the epilogue-overlap window.
// (R12/R13 bundled this with a sched_barrier-pinned reg double-buffer and
// hit back-to-back container failures; this round de-risks by submitting
// the swizzle alone on the last known-good source.)
// History: R18 vmcnt-ring, R19 512-thr, R22 SGB, R23 unpinned dbuf,
// R25 32x32 shape - all REVERTED null-or-worse. R24 mapping KEPT.
// ---------------------------------------------------------------------------
__global__ __launch_bounds__(256, 2) void gemm_pre(
    const float* __restrict__ ir, const float* __restrict__ ii,
    const v8h* __restrict__ yp,
    unsigned* __restrict__ cand, int tpc, int slots, int ch8)
{
    __shared__ unsigned xm[4][4][16][2];    // [wave][bt][col][a1,a2]  2 KB

    const int tid  = threadIdx.x;
    const int wave = tid >> 6, lane = tid & 63;
    const int quad = lane >> 4, col = lane & 15;

    // ---- chunk-per-XCD swizzle (bijective; enabled when CH % 8 == 0) ----
    // bid = bx + 128*by in [0, 128*CH); xcd = bid&7; ixc = bid>>3.
    // chunk = xcd + 8*(ixc>>7) in [0,CH); vox_blk = ixc&127.
    // Inverse: bid = 8*(128*(chunk>>3) + vox_blk) + (chunk&7) - bijective.
    int vox_blk, chunk;
    if (ch8) {
        const int bid = blockIdx.x + (int)gridDim.x * blockIdx.y;
        const int xcd = bid & 7;
        const int ixc = bid >> 3;
        chunk   = xcd + 8 * (ixc >> 7);
        vox_blk = ixc & 127;
    } else {
        vox_blk = blockIdx.x; chunk = blockIdx.y;
    }
    const int vox_w = vox_blk * 64;         // all 4 waves share the 64 voxels
    const int T0 = chunk * tpc;
    const int T1 = (T0 + tpc < NTILES) ? T0 + tpc : NTILES;

    // ---- persistent input B-frags: [arr][bt][h], bt = 0..3 (16 v8h) ----
    v8h fh[2][4][2];
#pragma unroll
    for (int arr = 0; arr < 2; ++arr) {
        const float* P = arr ? ii : ir;
#pragma unroll
        for (int bt = 0; bt < 4; ++bt) {
            const int b = vox_w + bt * 16 + col;
#pragma unroll
            for (int h = 0; h < 2; ++h) {
                v8h H;
#pragma unroll
                for (int j = 0; j < 8; ++j) {
                    const int k = h * 32 + quad * 8 + j;
                    H[j] = (_Float16)P[k * B_VOX + b];
                }
                fh[arr][bt][h] = H;
            }
        }
    }

    // ---- y A-frags: [ri][h], nrow = wave*16+col (4 v8h = 4 KB/tile) ----
    v8h yf[2][2];
    auto loadf = [&](int T) {
        const v8h* yv = (const v8h*)((const char*)yp + (size_t)T * 16384);
        const int nrow = wave * 16 + col;
#pragma unroll
        for (int ri = 0; ri < 2; ++ri)
#pragma unroll
            for (int h = 0; h < 2; ++h)
                yf[ri][h] = yv[((ri * 2 + h) * 4 + quad) * 64 + nrow];
    };

    const v4f zc = {0.f, 0.f, 0.f, 0.f};
    unsigned t2a[4] = {0u, 0u, 0u, 0u}, t2b[4] = {0u, 0u, 0u, 0u};

    loadf(T0);
    for (int T = T0; T < T1; ++T) {
        const int tl = T - T0;
        v4f acc[4][4];                      // [bt][rr,ri,s1,s2]
#define MF(A, B, C) __builtin_amdgcn_mfma_f32_16x16x32_f16(A, B, C, 0, 0, 0)
#pragma unroll
        for (int bt = 0; bt < 4; ++bt) {
            acc[bt][0] = MF(yf[0][0], fh[0][bt][0], zc);
            acc[bt][1] = MF(yf[1][0], fh[0][bt][0], zc);
            acc[bt][2] = MF(yf[0][0], fh[1][bt][0], zc);
            acc[bt][3] = MF(yf[1][0], fh[1][bt][0], zc);
        }
#pragma unroll
        for (int bt = 0; bt < 4; ++bt) {
            acc[bt][0] = MF(yf[0][1], fh[0][bt][1], acc[bt][0]);
            acc[bt][1] = MF(yf[1][1], fh[0][bt][1], acc[bt][1]);
            acc[bt][2] = MF(yf[0][1], fh[1][bt][1], acc[bt][2]);
            acc[bt][3] = MF(yf[1][1], fh[1][bt][1], acc[bt][3]);
        }
#undef MF
        // yf dead; issue next-tile loads so the epilogue runs under latency
        if (T + 1 < T1) loadf(T + 1);

        // ---- sim + top-2: packed-f32 sim, med3 second-best ----
        const unsigned base = 0x1FFFu
            - (unsigned)(tl * 64 + wave * 16 + quad * 4);
#pragma unroll
        for (int bt = 0; bt < 4; ++bt) {
            v2f s01, s23;
            {
                const v2f p0 = __builtin_shufflevector(acc[bt][0], acc[bt][0], 0, 1);
                const v2f p1 = __builtin_shufflevector(acc[bt][1], acc[bt][1], 0, 1);
                const v2f p2 = __builtin_shufflevector(acc[bt][2], acc[bt][2], 0, 1);
                const v2f p3 = __builtin_shufflevector(acc[bt][3], acc[bt][3], 0, 1);
                v2f s = p0 * p0;
                s = __builtin_elementwise_fma(p1, p1, s);
                s = __builtin_elementwise_fma(p2, p2, s);
                s = __builtin_elementwise_fma(p3, p3, s);
                s01 = s;
            }
            {
                const v2f p0 = __builtin_shufflevector(acc[bt][0], acc[bt][0], 2, 3);
                const v2f p1 = __builtin_shufflevector(acc[bt][1], acc[bt][1], 2, 3);
                const v2f p2 = __builtin_shufflevector(acc[bt][2], acc[bt][2], 2, 3);
                const v2f p3 = __builtin_shufflevector(acc[bt][3], acc[bt][3], 2, 3);
                v2f s = p0 * p0;
                s = __builtin_elementwise_fma(p1, p1, s);
                s = __builtin_elementwise_fma(p2, p2, s);
                s = __builtin_elementwise_fma(p3, p3, s);
                s23 = s;
            }
#pragma unroll
            for (int r = 0; r < 4; ++r) {       // 4 independent bt chains
                const float s = (r < 2) ? s01[r] : s23[r - 2];
                const unsigned pb = (__float_as_uint(s) & 0xFFFFE000u)
                                  | (base - (unsigned)r);
                const unsigned nb = umed3(pb, t2a[bt], t2b[bt]);  // 2nd-best
                t2a[bt] = umax32(pb, t2a[bt]);
                t2b[bt] = nb;
            }
        }
    }

    // ---- cross-lane top-2 merge over quads (lanes c, c+16, c+32, c+48) ----
    unsigned fa1[4], fa2[4];
#pragma unroll
    for (int bt = 0; bt < 4; ++bt) {
        unsigned a1 = t2a[bt], a2 = t2b[bt];
#pragma unroll
        for (int d = 16; d <= 32; d <<= 1) {
            unsigned b1 = (unsigned)__shfl_xor((int)a1, d, 64);
            unsigned b2 = (unsigned)__shfl_xor((int)a2, d, 64);
            unsigned mn = umin32(a1, b1);
            a1 = umax32(a1, b1);
            a2 = umax32(mn, umax32(a2, b2));
        }
        fa1[bt] = a1; fa2[bt] = a2;
    }
    // ---- cross-wave merge: all 4 waves publish, wave 0 merges 4-way ----
    if (lane < 16) {
#pragma unroll
        for (int bt = 0; bt < 4; ++bt) {
            xm[wave][bt][lane][0] = fa1[bt];
            xm[wave][bt][lane][1] = fa2[bt];
        }
    }
    __syncthreads();
    if (wave == 0 && lane < 16) {
#pragma unroll
        for (int bt = 0; bt < 4; ++bt) {
            unsigned m1 = 0u, m2 = 0u;
#pragma unroll
            for (int w = 0; w < 4; ++w) {
                const unsigned b1 = xm[w][bt][lane][0];
                const unsigned b2 = xm[w][bt][lane][1];
                m2 = umax32(m2, umax32(b2, umin32(m1, b1)));
                m1 = umax32(m1, b1);
            }
            const size_t vox = vox_w + bt * 16 + lane;
            cand[vox * slots + chunk * 2 + 0] = m1;
            cand[vox * slots + chunk * 2 + 1] = m2;
        }
    }
}

// ---------------------------------------------------------------------------
// Phase B (fused): exact fp32 rescore of candidates within 3% of approx max,
// winner lane computes scales and writes the 4 output rows directly.
// One wave per voxel.
// ---------------------------------------------------------------------------
__global__ __launch_bounds__(256) void rescore_finish(
    const float* __restrict__ ir, const float* __restrict__ ii,
    const float* __restrict__ yr, const float* __restrict__ yi,
    const float* __restrict__ inv, const float* __restrict__ x1,
    const float* __restrict__ x2,
    const unsigned* __restrict__ cand, int slots, int tpc,
    float* __restrict__ out)
{
    const int tid  = threadIdx.x;
    const int vox  = blockIdx.x * 4 + (tid >> 6);
    const int slot = tid & 63;

    unsigned p = (slot < slots) ? cand[(size_t)vox * slots + slot] : 0u;
    float sa = __uint_as_float(p & 0xFFFFE000u);
    const int chunkc = slot >> 1;
    const int nn = chunkc * tpc * 64 + (0x1FFF - (int)(p & 0x1FFFu));

    float amax = sa;
#pragma unroll
    for (int d = 1; d <= 32; d <<= 1) amax = fmaxf(amax, __shfl_xor(amax, d, 64));

    unsigned long long q = 0ull;
    float rr = 0.f, ri = 0.f, s1 = 0.f, s2 = 0.f;
    const bool active = (slot < slots) && (nn >= 0) && (nn < N_DICT)
                     && (sa >= 0.97f * amax);    // margin covers 1-term f16 error
    if (active) {
        for (int m = 0; m < M_TIME; ++m) {
            float a  = yr[(size_t)m * N_DICT + nn];
            float c  = yi[(size_t)m * N_DICT + nn];
            float vr = ir[m * B_VOX + vox];
            float vi = ii[m * B_VOX + vox];
            rr = fmaf(vr, a, rr); ri = fmaf(vr, c, ri);
            s1 = fmaf(vi, a, s1); s2 = fmaf(vi, c, s2);
        }
        float s = fmaf(rr, rr, fmaf(ri, ri, fmaf(s1, s1, s2 * s2)));
        q = (((unsigned long long)__float_as_uint(s)) << 32)
          | (unsigned long long)(0xFFFFFFFFu - (unsigned)nn);  // ties -> smaller n
    }
    unsigned long long qm = q;
#pragma unroll
    for (int d = 1; d <= 32; d <<= 1) qm = u64max(qm, __shfl_xor(qm, d, 64));

    if (active && q == qm && qm != 0ull) {       // exactly one lane (n in key)
        float ss = inv[nn];
        out[0 * B_VOX + vox] = (rr + s2) * ss;   // sum(yr*ir + yi*ii) * inv
        out[1 * B_VOX + vox] = (s1 - ri) * ss;   // sum(yr*ii - yi*ir) * inv
        out[2 * B_VOX + vox] = x1[nn];
        out[3 * B_VOX + vox] = x2[nn];
    }
}

// ---------------------------------------------------------------------------
// Last-resort fallbacks (tiny ws): fp32 brute-force argmax + finish.
// ---------------------------------------------------------------------------
__global__ __launch_bounds__(256, 3) void argmax_naive(
    const float* __restrict__ ir, const float* __restrict__ ii,
    const float* __restrict__ yr, const float* __restrict__ yi,
    int* __restrict__ idxout)
{
    int b = blockIdx.x * 256 + threadIdx.x;
    float bs = -1.0f; int bn = 0;
    for (int n = 0; n < N_DICT; ++n) {
        float a_rr = 0.f, a_ri = 0.f, a_s1 = 0.f, a_s2 = 0.f;
        for (int m = 0; m < M_TIME; ++m) {
            float a = yr[m * N_DICT + n], c = yi[m * N_DICT + n];
            float vr = ir[m * B_VOX + b], vi = ii[m * B_VOX + b];
            a_rr = fmaf(vr, a, a_rr); a_ri = fmaf(vr, c, a_ri);
            a_s1 = fmaf(vi, a, a_s1); a_s2 = fmaf(vi, c, a_s2);
        }
        float sim = fmaf(a_rr, a_rr, fmaf(a_ri, a_ri, fmaf(a_s1, a_s1, a_s2 * a_s2)));
        if (sim > bs) { bs = sim; bn = n; }
    }
    idxout[b] = bn;
}

__global__ void finish_k(const float* __restrict__ ir, const float* __restrict__ ii,
                         const float* __restrict__ yr, const float* __restrict__ yi,
                         const float* __restrict__ inv, const float* __restrict__ x1,
                         const float* __restrict__ x2,
                         const int* __restrict__ idxin, float* __restrict__ out)
{
    int b = blockIdx.x * blockDim.x + threadIdx.x;
    int idx = idxin[b];
    float ar = 0.f, ai = 0.f;
    for (int m = 0; m < M_TIME; ++m) {
        float a  = yr[(size_t)m * N_DICT + idx];
        float c  = yi[(size_t)m * N_DICT + idx];
        float vr = ir[m * B_VOX + b];
        float vi = ii[m * B_VOX + b];
        ar = fmaf(a, vr, ar); ar = fmaf(c, vi, ar);
        ai = fmaf(a, vi, ai); ai = fmaf(-c, vr, ai);
    }
    float s = inv[idx];
    out[0 * B_VOX + b] = ar * s;
    out[1 * B_VOX + b] = ai * s;
    out[2 * B_VOX + b] = x1[idx];
    out[3 * B_VOX + b] = x2[idx];
}

extern "C" void kernel_launch(void* const* d_in, const int* in_sizes, int n_in,
                              void* d_out, int out_size, void* d_ws, size_t ws_size,
                              hipStream_t stream) {
    const float* ir  = (const float*)d_in[0];
    const float* ii  = (const float*)d_in[1];
    const float* yr  = (const float*)d_in[2];
    const float* yi  = (const float*)d_in[3];
    const float* inv = (const float*)d_in[4];
    const float* x1  = (const float*)d_in[5];
    const float* x2  = (const float*)d_in[6];
    float* out = (float*)d_out;

    const size_t yp_bytes = (size_t)NTILES * 16384;    // 5.13 MB (f16 frag tiles)

    // pick largest chunk count whose cand buffer fits alongside yp (slots <= 64)
    int CH = 0;
    for (int c = 32; c >= 4; c >>= 1) {
        size_t cand_bytes = (size_t)B_VOX * (2 * c) * sizeof(unsigned);
        if (ws_size >= cand_bytes + yp_bytes) { CH = c; break; }
    }

    if (CH > 0) {
        const int slots = 2 * CH;
        const int tpc   = (NTILES + CH - 1) / CH;
        const int ch8   = (CH % 8 == 0) ? 1 : 0;
        unsigned* cand = (unsigned*)d_ws;
        v8h* yp = (v8h*)((char*)d_ws + (size_t)B_VOX * slots * sizeof(unsigned));

        const int units = 2 * NTILES * 512;
        split_y<<<(units + 255) / 256, 256, 0, stream>>>(yr, yi, yp);
        gemm_pre<<<dim3(B_VOX / 64, CH), 256, 0, stream>>>(ir, ii, yp, cand,
                                                           tpc, slots, ch8);
        rescore_finish<<<B_VOX / 4, 256, 0, stream>>>(ir, ii, yr, yi, inv, x1, x2,
                                                      cand, slots, tpc, out);
    } else {
        int* idxo = (int*)(out + 3 * B_VOX);   // alias out row 3 (read-before-write)
        argmax_naive<<<B_VOX / 256, 256, 0, stream>>>(ir, ii, yr, yi, idxo);
        finish_k<<<B_VOX / 256, 256, 0, stream>>>(ir, ii, yr, yi,
                                                  inv, x1, x2, idxo, out);
    }
}